// Round 5
// baseline (442.702 us; speedup 1.0000x reference)
//
#include <hip/hip_runtime.h>
#include <math.h>

typedef float f32x4 __attribute__((ext_vector_type(4)));

#define MAXNB 256   // max src buckets (nodes/256); 50000 nodes -> 196
#define BSHIFT 8    // 256 nodes per bucket: src-side rows/bucket = 256*768B = 192KB
#define UNROLL 8

// ---------- sort pipeline: bucket edges by src so G/K/V[src] gathers become
// ---------- L2-resident. R4 evidence: 576MB L2-miss fetch @ 4TB/s ceiling,
// ---------- more MLP didn't help -> reduce bytes, not latency.

__global__ void zero_kernel(int* p, int n) {
    int i = blockIdx.x * blockDim.x + threadIdx.x;
    if (i < n) p[i] = 0;
}

__global__ __launch_bounds__(256) void hist_kernel(
    const int* __restrict__ src, int nE, int nb, int* __restrict__ counts)
{
    __shared__ int lc[MAXNB];
    for (int i = threadIdx.x; i < nb; i += blockDim.x) lc[i] = 0;
    __syncthreads();
    for (int e = blockIdx.x * blockDim.x + threadIdx.x; e < nE;
         e += gridDim.x * blockDim.x)
        atomicAdd(&lc[src[e] >> BSHIFT], 1);
    __syncthreads();
    for (int i = threadIdx.x; i < nb; i += blockDim.x) {
        int c = lc[i];
        if (c) atomicAdd(&counts[i], c);
    }
}

// exclusive scan of counts -> cursor (nb <= 256, one block)
__global__ __launch_bounds__(256) void scan_kernel(
    const int* __restrict__ counts, int nb, int* __restrict__ cursor)
{
    __shared__ int buf[MAXNB];
    int t = threadIdx.x;
    int v = (t < nb) ? counts[t] : 0;
    buf[t] = v;
    __syncthreads();
    #pragma unroll
    for (int off = 1; off < MAXNB; off <<= 1) {
        int x = (t >= off) ? buf[t - off] : 0;
        __syncthreads();
        buf[t] += x;
        __syncthreads();
    }
    if (t < nb) cursor[t] = buf[t] - v;   // exclusive
}

// block-aggregated scatter: LDS histogram per 2048-edge chunk, ONE global
// atomic per (bucket,chunk) -> ~100k global atomics total instead of 1M.
// Also writes bucket-sorted copies of src/dst so the main kernel reads
// them coalesced.
__global__ __launch_bounds__(256) void scatter_kernel(
    const int* __restrict__ src, const int* __restrict__ dst, int nE, int nb,
    int* __restrict__ cursor, int* __restrict__ perm,
    int* __restrict__ ssrc, int* __restrict__ sdst)
{
    __shared__ int lc[MAXNB];
    __shared__ int lb[MAXNB];
    const int chunkSize = blockDim.x * UNROLL;
    for (int chunk = blockIdx.x * chunkSize; chunk < nE;
         chunk += gridDim.x * chunkSize) {
        for (int i = threadIdx.x; i < nb; i += blockDim.x) lc[i] = 0;
        __syncthreads();
        int myb[UNROLL], myoff[UNROLL], mys[UNROLL], myd[UNROLL];
        #pragma unroll
        for (int u = 0; u < UNROLL; u++) {
            int e = chunk + u * blockDim.x + threadIdx.x;
            if (e < nE) {
                int s = src[e];
                mys[u] = s; myd[u] = dst[e];
                myb[u] = s >> BSHIFT;
                myoff[u] = atomicAdd(&lc[myb[u]], 1);
            } else myb[u] = -1;
        }
        __syncthreads();
        for (int i = threadIdx.x; i < nb; i += blockDim.x) {
            int c = lc[i];
            lb[i] = c ? atomicAdd(&cursor[i], c) : 0;
        }
        __syncthreads();
        #pragma unroll
        for (int u = 0; u < UNROLL; u++) {
            if (myb[u] >= 0) {
                int pos = lb[myb[u]] + myoff[u];
                int e = chunk + u * blockDim.x + threadIdx.x;
                perm[pos] = e; ssrc[pos] = mys[u]; sdst[pos] = myd[u];
            }
        }
        __syncthreads();
    }
}

// main: process edges in src-bucket order. 16 lanes per edge (f32x4/lane =
// 256B coalesced row), 4 edges per wave. Output scattered via perm (256B NT
// stores, full burst efficiency).
__global__ __launch_bounds__(256) void edge_message_kernel(
    const float* __restrict__ G,
    const float* __restrict__ K,
    const float* __restrict__ Q,
    const float* __restrict__ V,
    const int* __restrict__ perm,
    const int* __restrict__ ssrc,
    const int* __restrict__ sdst,
    float* __restrict__ out,
    int nE)
{
    const int tid  = threadIdx.x;
    const int lane = tid & 63;
    const int grp  = lane >> 4;
    const int sub  = lane & 15;
    const int wavesPerBlock = blockDim.x >> 6;
    const int waveId = blockIdx.x * wavesPerBlock + (tid >> 6);
    const int waveStride = gridDim.x * wavesPerBlock;

    const f32x4* __restrict__ G4 = (const f32x4*)G;
    const f32x4* __restrict__ K4 = (const f32x4*)K;
    const f32x4* __restrict__ Q4 = (const f32x4*)Q;
    const f32x4* __restrict__ V4 = (const f32x4*)V;
    f32x4* __restrict__ out4 = (f32x4*)out;

    const float inv_sqrt_d = 0.125f;
    const int last = nE - 1;

    for (int i0 = waveId * 4; i0 < nE; i0 += waveStride * 4) {
        const int i = i0 + grp;
        const bool valid = (i < nE);
        const int ic = valid ? i : last;

        // 16 lanes of a group read the same slot -> HW broadcast
        const int s = ssrc[ic];
        const int d = sdst[ic];
        const int o = perm[ic];

        const f32x4 gs = G4[s * 16 + sub];
        const f32x4 gd = G4[d * 16 + sub];
        const f32x4 ks = K4[s * 16 + sub];
        const f32x4 qd = Q4[d * 16 + sub];
        const f32x4 vs = V4[s * 16 + sub];

        const f32x4 df = gs - gd;
        const f32x4 kq = ks * qd;
        float a = df.x * df.x + df.y * df.y + df.z * df.z + df.w * df.w;
        float b = kq.x + kq.y + kq.z + kq.w;

        #pragma unroll
        for (int off = 8; off > 0; off >>= 1) {
            a += __shfl_xor(a, off, 64);
            b += __shfl_xor(b, off, 64);
        }

        float t1 = -sqrtf(a + 1e-6f) * inv_sqrt_d;
        t1 = fminf(fmaxf(t1, -5.0f), 5.0f);
        float t2 = b * inv_sqrt_d;
        t2 = fminf(fmaxf(t2, -5.0f), 5.0f);
        const float w = __expf(t1 + t2);

        if (valid) {
            __builtin_nontemporal_store(w * vs, &out4[(size_t)o * 16 + sub]);
        }
    }
}

extern "C" void kernel_launch(void* const* d_in, const int* in_sizes, int n_in,
                              void* d_out, int out_size, void* d_ws, size_t ws_size,
                              hipStream_t stream)
{
    const float* G   = (const float*)d_in[0];
    const float* K   = (const float*)d_in[1];
    const float* Q   = (const float*)d_in[2];
    const float* V   = (const float*)d_in[3];
    const int*   src = (const int*)d_in[4];
    const int*   dst = (const int*)d_in[5];
    float* out = (float*)d_out;

    const int nE = in_sizes[4];
    const int nNodes = in_sizes[0] / 64;
    const int nb = (nNodes + ((1 << BSHIFT) - 1)) >> BSHIFT;  // <= MAXNB

    // workspace layout (d_ws re-poisoned 0xAA every call -> zero what we use)
    int* counts = (int*)d_ws;            // [256]
    int* cursor = counts + 256;          // [256]
    int* perm   = cursor + 256;          // [nE]
    int* ssrc   = perm + nE;             // [nE]
    int* sdst   = ssrc + nE;             // [nE]

    zero_kernel<<<2, 256, 0, stream>>>(counts, 512);
    hist_kernel<<<256, 256, 0, stream>>>(src, nE, nb, counts);
    scan_kernel<<<1, 256, 0, stream>>>(counts, nb, cursor);
    {
        const int chunk = 256 * UNROLL;
        int grid = (nE + chunk - 1) / chunk;
        scatter_kernel<<<grid, 256, 0, stream>>>(src, dst, nE, nb,
                                                 cursor, perm, ssrc, sdst);
    }
    {
        const int block = 256;                    // 4 waves, 16 edges/block
        const int edgesPerBlock = (block / 64) * 4;
        int grid = (nE + edgesPerBlock - 1) / edgesPerBlock;
        if (grid > 2048) grid = 2048;
        edge_message_kernel<<<grid, block, 0, stream>>>(G, K, Q, V,
                                                        perm, ssrc, sdst, out, nE);
    }
}

// Round 7
// 433.049 us; speedup vs baseline: 1.0223x; 1.0223x over previous
//
#include <hip/hip_runtime.h>
#include <math.h>

typedef float f32x4 __attribute__((ext_vector_type(4)));

#define MAXNB 256   // max src buckets; 50000 nodes @ 256/bucket -> 196
#define BSHIFT 8
#define UNROLL 8

// R5 evidence: all configs pin at ~4.1 TB/s of TCC traffic; time ~ bytes.
// Remaining fetch: dst-side ~230MB (compulsory-ish), src-side ~150MB vs 38MB
// compulsory (8-XCD L2 replication). Fix: chunk sorted edges per XCD.
// Also: s,d < 2^16 -> pack record as int2{s|(d<<16), orig_e} (8B/edge).

__global__ void zero_kernel(int* p, int n) {
    int i = blockIdx.x * blockDim.x + threadIdx.x;
    if (i < n) p[i] = 0;
}

__global__ __launch_bounds__(256) void hist_kernel(
    const int* __restrict__ src, int nE, int nb, int* __restrict__ counts)
{
    __shared__ int lc[MAXNB];
    for (int i = threadIdx.x; i < nb; i += blockDim.x) lc[i] = 0;
    __syncthreads();
    for (int e = blockIdx.x * blockDim.x + threadIdx.x; e < nE;
         e += gridDim.x * blockDim.x)
        atomicAdd(&lc[src[e] >> BSHIFT], 1);
    __syncthreads();
    for (int i = threadIdx.x; i < nb; i += blockDim.x) {
        int c = lc[i];
        if (c) atomicAdd(&counts[i], c);
    }
}

__global__ __launch_bounds__(256) void scan_kernel(
    const int* __restrict__ counts, int nb, int* __restrict__ cursor)
{
    __shared__ int buf[MAXNB];
    int t = threadIdx.x;
    int v = (t < nb) ? counts[t] : 0;
    buf[t] = v;
    __syncthreads();
    #pragma unroll
    for (int off = 1; off < MAXNB; off <<= 1) {
        int x = (t >= off) ? buf[t - off] : 0;
        __syncthreads();
        buf[t] += x;
        __syncthreads();
    }
    if (t < nb) cursor[t] = buf[t] - v;   // exclusive
}

// block-aggregated scatter: one global atomic per (bucket,chunk).
// Writes packed int2 records {src|dst<<16, orig_e} in bucket order.
__global__ __launch_bounds__(256) void scatter_kernel(
    const int* __restrict__ src, const int* __restrict__ dst, int nE, int nb,
    int* __restrict__ cursor, int2* __restrict__ eidx)
{
    __shared__ int lc[MAXNB];
    __shared__ int lb[MAXNB];
    const int chunkSize = blockDim.x * UNROLL;
    for (int chunk = blockIdx.x * chunkSize; chunk < nE;
         chunk += gridDim.x * chunkSize) {
        for (int i = threadIdx.x; i < nb; i += blockDim.x) lc[i] = 0;
        __syncthreads();
        int myb[UNROLL], myoff[UNROLL], pack[UNROLL];
        #pragma unroll
        for (int u = 0; u < UNROLL; u++) {
            int e = chunk + u * blockDim.x + threadIdx.x;
            if (e < nE) {
                int s = src[e];
                pack[u] = s | (dst[e] << 16);      // s,d < 65536
                myb[u] = s >> BSHIFT;
                myoff[u] = atomicAdd(&lc[myb[u]], 1);
            } else myb[u] = -1;
        }
        __syncthreads();
        for (int i = threadIdx.x; i < nb; i += blockDim.x) {
            int c = lc[i];
            lb[i] = c ? atomicAdd(&cursor[i], c) : 0;
        }
        __syncthreads();
        #pragma unroll
        for (int u = 0; u < UNROLL; u++) {
            if (myb[u] >= 0) {
                int pos = lb[myb[u]] + myoff[u];
                int e = chunk + u * blockDim.x + threadIdx.x;
                eidx[pos] = make_int2(pack[u], e);
            }
        }
        __syncthreads();
    }
}

// main: each block owns a CONTIGUOUS range of sorted edges; ranges are
// swizzled so blocks on the same XCD (bid%8) cover a contiguous eighth of
// the sorted order -> each src-bucket's rows enter ~1 private L2, not 8.
// 16 lanes per edge (f32x4/lane = 256B row), 16 edge slots per 256-thr block.
__global__ __launch_bounds__(256) void edge_message_kernel(
    const float* __restrict__ G,
    const float* __restrict__ K,
    const float* __restrict__ Q,
    const float* __restrict__ V,
    const int2* __restrict__ eidx,
    float* __restrict__ out,
    int nE)
{
    const int tid  = threadIdx.x;
    const int slot = tid >> 4;    // 0..15 (16-lane groups, aligned to waves)
    const int sub  = tid & 15;

    const int nx = gridDim.x >> 3;                       // blocks per XCD
    const int chunkIdx = (blockIdx.x & 7) * nx + (blockIdx.x >> 3);
    const int perBlock = (nE + gridDim.x - 1) / gridDim.x;
    const int start = chunkIdx * perBlock;
    const int end   = min(start + perBlock, nE);

    const f32x4* __restrict__ G4 = (const f32x4*)G;
    const f32x4* __restrict__ K4 = (const f32x4*)K;
    const f32x4* __restrict__ Q4 = (const f32x4*)Q;
    const f32x4* __restrict__ V4 = (const f32x4*)V;
    f32x4* __restrict__ out4 = (f32x4*)out;

    const float inv_sqrt_d = 0.125f;

    for (int i0 = start; i0 < end; i0 += 16) {
        const int i = i0 + slot;
        const bool valid = (i < end);
        const int ic = valid ? i : (end - 1);

        const int2 rec = eidx[ic];            // 8B, coalesced across slots
        const unsigned u = (unsigned)rec.x;
        const int s = (int)(u & 0xFFFFu);
        const int d = (int)(u >> 16);
        const int o = rec.y;

        const f32x4 gs = G4[s * 16 + sub];
        const f32x4 gd = G4[d * 16 + sub];
        const f32x4 ks = K4[s * 16 + sub];
        const f32x4 qd = Q4[d * 16 + sub];
        const f32x4 vs = V4[s * 16 + sub];

        const f32x4 df = gs - gd;
        const f32x4 kq = ks * qd;
        float a = df.x * df.x + df.y * df.y + df.z * df.z + df.w * df.w;
        float b = kq.x + kq.y + kq.z + kq.w;

        #pragma unroll
        for (int off = 8; off > 0; off >>= 1) {
            a += __shfl_xor(a, off, 64);
            b += __shfl_xor(b, off, 64);
        }

        float t1 = -sqrtf(a + 1e-6f) * inv_sqrt_d;
        t1 = fminf(fmaxf(t1, -5.0f), 5.0f);
        float t2 = b * inv_sqrt_d;
        t2 = fminf(fmaxf(t2, -5.0f), 5.0f);
        const float w = __expf(t1 + t2);

        if (valid) {
            __builtin_nontemporal_store(w * vs, &out4[(size_t)o * 16 + sub]);
        }
    }
}

extern "C" void kernel_launch(void* const* d_in, const int* in_sizes, int n_in,
                              void* d_out, int out_size, void* d_ws, size_t ws_size,
                              hipStream_t stream)
{
    const float* G   = (const float*)d_in[0];
    const float* K   = (const float*)d_in[1];
    const float* Q   = (const float*)d_in[2];
    const float* V   = (const float*)d_in[3];
    const int*   src = (const int*)d_in[4];
    const int*   dst = (const int*)d_in[5];
    float* out = (float*)d_out;

    const int nE = in_sizes[4];
    const int nNodes = in_sizes[0] / 64;
    const int nb = (nNodes + ((1 << BSHIFT) - 1)) >> BSHIFT;  // <= MAXNB

    // workspace: counts[256] | cursor[256] | eidx[nE] (8B-aligned at +2048)
    int* counts = (int*)d_ws;
    int* cursor = counts + 256;
    int2* eidx  = (int2*)(counts + 512);

    zero_kernel<<<2, 256, 0, stream>>>(counts, 512);
    hist_kernel<<<256, 256, 0, stream>>>(src, nE, nb, counts);
    scan_kernel<<<1, 256, 0, stream>>>(counts, nb, cursor);
    {
        const int chunk = 256 * UNROLL;
        int grid = (nE + chunk - 1) / chunk;
        scatter_kernel<<<grid, 256, 0, stream>>>(src, dst, nE, nb, cursor, eidx);
    }
    {
        int grid = 2048;                       // multiple of 8 for XCD chunking
        edge_message_kernel<<<grid, 256, 0, stream>>>(G, K, Q, V, eidx, out, nE);
    }
}